// Round 4
// baseline (138.688 us; speedup 1.0000x reference)
//
#include <hip/hip_runtime.h>

constexpr int NL = 256;   // lights
constexpr int HW = 256;   // H == W
constexpr int NKEY = 65536;   // (i0<<8) | y0

// 8-byte value with 4-byte alignment (x-pair load)
struct __attribute__((aligned(4))) F2 { float a, b; };

struct alignas(16) Rec {
    float px, py, w0, w1, w2;
    unsigned meta;   // i0 | i1<<8 | i2<<16 | y0<<24
    unsigned p;      // original point index
    unsigned pad;
};

// ---------------- pass 1: scan + record + bucket count ----------------
__global__ __launch_bounds__(256)
void k_scan(const float* __restrict__ X,
            const float* __restrict__ lpos,
            Rec* __restrict__ recs,
            unsigned* __restrict__ count, int B)
{
    __shared__ float2 s_lp[NL];
    for (int i = threadIdx.x; i < NL; i += 256)
        s_lp[i] = reinterpret_cast<const float2*>(lpos)[i];
    __syncthreads();

    int b = blockIdx.x * 256 + threadIdx.x;
    if (b >= B) return;

    float4 xv = reinterpret_cast<const float4*>(X)[b];
    float qx = xv.z, qy = xv.w;

    float dd0 = INFINITY, dd1 = INFINITY, dd2 = INFINITY;
    int i0 = 0, i1 = 0, i2 = 0;
    #pragma unroll 4
    for (int i = 0; i < NL; ++i) {
        float2 lp = s_lp[i];
        float dx = qx - lp.x, dy = qy - lp.y;
        float d = dx * dx + dy * dy;
        bool c0 = d < dd0, c1 = d < dd1, c2 = d < dd2;
        dd2 = c1 ? dd1 : (c2 ? d : dd2);
        i2  = c1 ? i1  : (c2 ? i : i2);
        dd1 = c0 ? dd0 : (c1 ? d : dd1);
        i1  = c0 ? i0  : (c1 ? i : i1);
        dd0 = c0 ? d   : dd0;
        i0  = c0 ? i   : i0;
    }

    // barycentric weights (branchless fallback; NaN -> fallback)
    float2 p0 = s_lp[i0], p1 = s_lp[i1], p2c = s_lp[i2];
    float v0x = p1.x - p0.x,  v0y = p1.y - p0.y;
    float v1x = p2c.x - p0.x, v1y = p2c.y - p0.y;
    float v2x = qx - p0.x,    v2y = qy - p0.y;
    float d00 = v0x * v0x + v0y * v0y;
    float d11 = v1x * v1x + v1y * v1y;
    float d01 = v0x * v1x + v0y * v1y;
    float d20 = v2x * v0x + v2y * v0y;
    float d21 = v2x * v1x + v2y * v1y;
    float denom = d00 * d11 - d01 * d01;
    float v = (d11 * d20 - d01 * d21) / denom;
    float w = (d00 * d21 - d01 * d20) / denom;
    float u = 1.0f - v - w;
    bool inside = (u >= 0.f) & (v >= 0.f) & (w >= 0.f);
    float t = fminf(fmaxf(d20 / d00, 0.f), 1.f);
    float w0 = inside ? u : (1.f - t);
    float w1 = inside ? v : t;
    float w2 = inside ? w : 0.f;

    float px = fminf(fmaxf((xv.x + 1.f) * 0.5f * (HW - 1), 0.f), (float)(HW - 1));
    float py = fminf(fmaxf((xv.y + 1.f) * 0.5f * (HW - 1), 0.f), (float)(HW - 1));
    int y0 = (int)floorf(py);

    Rec r;
    r.px = px; r.py = py; r.w0 = w0; r.w1 = w1; r.w2 = w2;
    r.meta = (unsigned)i0 | ((unsigned)i1 << 8) | ((unsigned)i2 << 16) |
             ((unsigned)y0 << 24);
    r.p = (unsigned)b; r.pad = 0;
    recs[b] = r;

    unsigned key = ((unsigned)i0 << 8) | (unsigned)y0;
    atomicAdd(&count[key], 1u);
}

// ---------------- pass 2: exclusive prefix over 65536 counts ----------------
__global__ __launch_bounds__(1024)
void k_prefix(unsigned* __restrict__ count)
{
    __shared__ unsigned part[1024];
    int t = threadIdx.x;
    unsigned local[64];
    unsigned base = 0;
    for (int j = 0; j < 64; ++j) {
        local[j] = count[t * 64 + j];
        base += local[j];
    }
    part[t] = base;
    __syncthreads();
    // Hillis-Steele inclusive scan over 1024 partials
    for (int off = 1; off < 1024; off <<= 1) {
        unsigned nv = part[t];
        if (t >= off) nv += part[t - off];
        __syncthreads();
        part[t] = nv;
        __syncthreads();
    }
    unsigned run = (t == 0) ? 0u : part[t - 1];
    for (int j = 0; j < 64; ++j) {
        unsigned c = local[j];
        count[t * 64 + j] = run;
        run += c;
    }
}

// ---------------- pass 3: counting-sort scatter ----------------
__global__ __launch_bounds__(256)
void k_scatter(const Rec* __restrict__ recs,
               unsigned* __restrict__ count,
               Rec* __restrict__ sorted, int B)
{
    int b = blockIdx.x * 256 + threadIdx.x;
    if (b >= B) return;
    Rec r = recs[b];
    unsigned key = ((r.meta & 255u) << 8) | (r.meta >> 24);
    unsigned slot = atomicAdd(&count[key], 1u);
    sorted[slot] = r;
}

// ---------------- pass 4: locality-sorted gather ----------------
__global__ __launch_bounds__(256, 4)
void k_gather(const Rec* __restrict__ sorted,
              const float* __restrict__ shots,
              float* __restrict__ out, int B, int nwg)
{
    int bid = blockIdx.x;
    int g = bid;
    if ((nwg & 7) == 0) {                 // XCD-chunked swizzle (bijective)
        int chunk = nwg >> 3;
        g = (bid & 7) * chunk + (bid >> 3);
    }
    int idx = g * 256 + threadIdx.x;
    if (idx >= B) return;

    Rec r = sorted[idx];
    float px = r.px, py = r.py;
    int x0 = (int)floorf(px), y0 = (int)floorf(py);
    int y1 = min(y0 + 1, HW - 1);
    float wx = px - (float)x0, wy = py - (float)y0;
    float w00 = (1.f - wy) * (1.f - wx), w01 = (1.f - wy) * wx;
    float w10 = wy * (1.f - wx),         w11 = wy * wx;
    int  xe  = min(x0, HW - 2);
    bool xhi = (x0 == HW - 1);

    unsigned m = r.meta;
    int   li[3] = { (int)(m & 255u), (int)((m >> 8) & 255u), (int)((m >> 16) & 255u) };
    float wk[3] = { r.w0, r.w1, r.w2 };

    F2 G0[9], G1[9];
    #pragma unroll
    for (int k = 0; k < 3; ++k) {
        const float* base = shots + (size_t)li[k] * (3 * HW * HW);
        #pragma unroll
        for (int c = 0; c < 3; ++c) {
            const float* p = base + c * (HW * HW) + xe;
            int j = k * 3 + c;
            G0[j] = *reinterpret_cast<const F2*>(p + y0 * HW);
            G1[j] = *reinterpret_cast<const F2*>(p + y1 * HW);
        }
    }

    float acc[3] = { 0.f, 0.f, 0.f };
    #pragma unroll
    for (int k = 0; k < 3; ++k) {
        #pragma unroll
        for (int c = 0; c < 3; ++c) {
            int j = k * 3 + c;
            float v00 = xhi ? G0[j].b : G0[j].a;
            float v10 = xhi ? G1[j].b : G1[j].a;
            float col = v00 * w00 + G0[j].b * w01 +
                        v10 * w10 + G1[j].b * w11;
            acc[c] += wk[k] * col;
        }
    }

    size_t p = (size_t)r.p;
    out[p * 3 + 0] = acc[0];
    out[p * 3 + 1] = acc[1];
    out[p * 3 + 2] = acc[2];
}

// ---------------- fallback: fused single kernel (ws too small) ----------------
__global__ __launch_bounds__(256, 4)
void lsf_fused(const float* __restrict__ X,
               const float* __restrict__ shots,
               const float* __restrict__ lpos,
               float* __restrict__ out, int B)
{
    __shared__ float2 s_lp[NL];
    for (int i = threadIdx.x; i < NL; i += 256)
        s_lp[i] = reinterpret_cast<const float2*>(lpos)[i];
    __syncthreads();

    int b = blockIdx.x * 256 + threadIdx.x;
    if (b >= B) return;
    float4 xv = reinterpret_cast<const float4*>(X)[b];
    float qx = xv.z, qy = xv.w;

    float dd0 = INFINITY, dd1 = INFINITY, dd2 = INFINITY;
    int i0 = 0, i1 = 0, i2 = 0;
    #pragma unroll 4
    for (int i = 0; i < NL; ++i) {
        float2 lp = s_lp[i];
        float dx = qx - lp.x, dy = qy - lp.y;
        float d = dx * dx + dy * dy;
        bool c0 = d < dd0, c1 = d < dd1, c2 = d < dd2;
        dd2 = c1 ? dd1 : (c2 ? d : dd2);
        i2  = c1 ? i1  : (c2 ? i : i2);
        dd1 = c0 ? dd0 : (c1 ? d : dd1);
        i1  = c0 ? i0  : (c1 ? i : i1);
        dd0 = c0 ? d   : dd0;
        i0  = c0 ? i   : i0;
    }

    float2 p0 = s_lp[i0], p1 = s_lp[i1], p2c = s_lp[i2];
    float v0x = p1.x - p0.x,  v0y = p1.y - p0.y;
    float v1x = p2c.x - p0.x, v1y = p2c.y - p0.y;
    float v2x = qx - p0.x,    v2y = qy - p0.y;
    float d00 = v0x * v0x + v0y * v0y;
    float d11 = v1x * v1x + v1y * v1y;
    float d01 = v0x * v1x + v0y * v1y;
    float d20 = v2x * v0x + v2y * v0y;
    float d21 = v2x * v1x + v2y * v1y;
    float denom = d00 * d11 - d01 * d01;
    float v = (d11 * d20 - d01 * d21) / denom;
    float w = (d00 * d21 - d01 * d20) / denom;
    float u = 1.0f - v - w;
    bool inside = (u >= 0.f) & (v >= 0.f) & (w >= 0.f);
    float t = fminf(fmaxf(d20 / d00, 0.f), 1.f);
    float w0 = inside ? u : (1.f - t);
    float w1 = inside ? v : t;
    float w2 = inside ? w : 0.f;

    float px = fminf(fmaxf((xv.x + 1.f) * 0.5f * (HW - 1), 0.f), (float)(HW - 1));
    float py = fminf(fmaxf((xv.y + 1.f) * 0.5f * (HW - 1), 0.f), (float)(HW - 1));
    int x0 = (int)floorf(px), y0 = (int)floorf(py);
    int y1 = min(y0 + 1, HW - 1);
    float wx = px - (float)x0, wy = py - (float)y0;
    float w00 = (1.f - wy) * (1.f - wx), w01 = (1.f - wy) * wx;
    float w10 = wy * (1.f - wx),         w11 = wy * wx;
    int  xe  = min(x0, HW - 2);
    bool xhi = (x0 == HW - 1);

    int   idx3[3] = { i0, i1, i2 };
    float wk3[3]  = { w0, w1, w2 };
    F2 G0[9], G1[9];
    #pragma unroll
    for (int k = 0; k < 3; ++k) {
        const float* base = shots + (size_t)idx3[k] * (3 * HW * HW);
        #pragma unroll
        for (int c = 0; c < 3; ++c) {
            const float* p = base + c * (HW * HW) + xe;
            int j = k * 3 + c;
            G0[j] = *reinterpret_cast<const F2*>(p + y0 * HW);
            G1[j] = *reinterpret_cast<const F2*>(p + y1 * HW);
        }
    }
    float acc[3] = { 0.f, 0.f, 0.f };
    #pragma unroll
    for (int k = 0; k < 3; ++k)
        #pragma unroll
        for (int c = 0; c < 3; ++c) {
            int j = k * 3 + c;
            float v00 = xhi ? G0[j].b : G0[j].a;
            float v10 = xhi ? G1[j].b : G1[j].a;
            acc[c] += wk3[k] * (v00 * w00 + G0[j].b * w01 +
                                v10 * w10 + G1[j].b * w11);
        }
    out[(size_t)b * 3 + 0] = acc[0];
    out[(size_t)b * 3 + 1] = acc[1];
    out[(size_t)b * 3 + 2] = acc[2];
}

extern "C" void kernel_launch(void* const* d_in, const int* in_sizes, int n_in,
                              void* d_out, int out_size, void* d_ws, size_t ws_size,
                              hipStream_t stream) {
    const float* X     = (const float*)d_in[0];
    const float* shots = (const float*)d_in[1];
    const float* lpos  = (const float*)d_in[2];
    float* out = (float*)d_out;
    int B = in_sizes[0] / 4;
    int nwg = (B + 255) / 256;

    size_t off_count  = 0;
    size_t off_recs   = (size_t)NKEY * sizeof(unsigned);            // 256 KB
    size_t off_sorted = off_recs + (size_t)B * sizeof(Rec);
    size_t need       = off_sorted + (size_t)B * sizeof(Rec);

    if (ws_size >= need) {
        unsigned* count = (unsigned*)((char*)d_ws + off_count);
        Rec* recs   = (Rec*)((char*)d_ws + off_recs);
        Rec* sorted = (Rec*)((char*)d_ws + off_sorted);
        hipMemsetAsync(count, 0, (size_t)NKEY * sizeof(unsigned), stream);
        k_scan<<<nwg, 256, 0, stream>>>(X, lpos, recs, count, B);
        k_prefix<<<1, 1024, 0, stream>>>(count);
        k_scatter<<<nwg, 256, 0, stream>>>(recs, count, sorted, B);
        k_gather<<<nwg, 256, 0, stream>>>(sorted, shots, out, B, nwg);
    } else {
        lsf_fused<<<nwg, 256, 0, stream>>>(X, shots, lpos, out, B);
    }
}